// Round 4
// baseline (528.665 us; speedup 1.0000x reference)
//
#include <hip/hip_runtime.h>

#define EPSF 1e-12f
#define NT1 512
#define T1STR 340
#define T2STR 264

typedef __attribute__((ext_vector_type(8))) short short8;     // MFMA bf16 A/B frag
typedef __attribute__((ext_vector_type(4))) float f32x4;      // MFMA C/D frag
typedef __attribute__((ext_vector_type(4))) unsigned int uint4v;

__device__ __forceinline__ unsigned f2bf(float f) {
    unsigned u = __float_as_uint(f);
    return (u + 0x7FFFu + ((u >> 16) & 1u)) >> 16;
}
__device__ __forceinline__ float bf2f(unsigned h) { return __uint_as_float(h << 16); }
__device__ __forceinline__ short8 asbf(uint4v u) { return __builtin_bit_cast(short8, u); }

// ===========================================================================
// FAST PATH
// ===========================================================================

// ---------------------------------------------------------------------------
// kA: x[b][c][px] fp32  ->  xh,xl planes [b][px][64c] bf16 (split hi/lo)
// Grid: 1024 blocks x 256 thr.  (proven in round 3)
// ---------------------------------------------------------------------------
__global__ __launch_bounds__(256)
void kA_split(const float* __restrict__ x, unsigned short* __restrict__ xh,
              unsigned short* __restrict__ xl)
{
    __shared__ float xt[64][257];
    const int blk = blockIdx.x, tid = threadIdx.x;
    const int b = blk >> 8, chunk = blk & 255;
    const int px0 = chunk * 256;
    const float* xb = x + ((size_t)b << 22);
    for (int c = 0; c < 64; ++c)
        xt[c][tid] = xb[((size_t)c << 16) + px0 + tid];
    __syncthreads();
    const int px = px0 + tid;
    unsigned hbuf[32], lbuf[32];
    #pragma unroll
    for (int j = 0; j < 32; ++j) {
        float f0 = xt[2*j][tid], f1 = xt[2*j+1][tid];
        unsigned h0 = f2bf(f0), h1 = f2bf(f1);
        float r0 = f0 - bf2f(h0), r1 = f1 - bf2f(h1);
        hbuf[j] = (h1 << 16) | h0;
        lbuf[j] = (f2bf(r1) << 16) | f2bf(r0);
    }
    size_t row = ((size_t)(b << 16) + px) * 64;   // in shorts
    uint4v* dh = (uint4v*)(xh + row);
    uint4v* dl = (uint4v*)(xl + row);
    #pragma unroll
    for (int j = 0; j < 8; ++j) {
        uint4v vh, vl;
        vh[0]=hbuf[4*j]; vh[1]=hbuf[4*j+1]; vh[2]=hbuf[4*j+2]; vh[3]=hbuf[4*j+3];
        vl[0]=lbuf[4*j]; vl[1]=lbuf[4*j+1]; vl[2]=lbuf[4*j+2]; vl[3]=lbuf[4*j+3];
        dh[j] = vh; dl[j] = vl;
    }
}

// ---------------------------------------------------------------------------
// kF: fused  t = W@x (MFMA, split-bf16) -> dw 3x3 -> gate -> v(global, packed),
//     G-partial = q.v^T (MFMA), |q|^2,|v|^2.
// Tile: 8 rows x 32 px (center 256 px), halo 10x34 = 340 px.
// Grid: 1024 blocks (4 batches x 256 tiles) x 256 thr (4 waves).
// Wave w owns qv channels 32w..32w+31 through phases 1-3 (no barrier needed);
// single barrier before the cross-wave G phase.
// LDS: t1s 87040 + t2s 67584 + wds 4608 = 159232 B.
// ---------------------------------------------------------------------------
__global__ __launch_bounds__(256, 1)
void kF_fused(const unsigned short* __restrict__ xh, const unsigned short* __restrict__ xl,
              const float* __restrict__ w_in, const float* __restrict__ w_dw,
              unsigned* __restrict__ vpk, float* __restrict__ Gpart,
              float* __restrict__ sqq, float* __restrict__ sqv)
{
    __shared__ unsigned short t1s[128 * T1STR];   // [dw-ch][halo-flat 340]
    __shared__ unsigned short t2s[128 * T2STR];   // [qv-ch][center 256] (pad 264)
    __shared__ float wds[128][9];

    const int tid = threadIdx.x;
    const int wv = tid >> 6, lane = tid & 63;
    const int l15 = lane & 15, l4 = lane >> 4;

    const int blk = blockIdx.x;
    const int b = blk >> 8;               // 256 tiles per batch
    const int tile = blk & 255;
    const int y0 = (tile >> 3) << 3;      // 32 row-tiles of 8
    const int x0 = (tile & 7) << 5;       // 8 col-tiles of 32

    // dw weights: each wave loads its own 32 channels (wave-private use)
    const int chbase = 32 * wv;
    for (int i = lane; i < 288; i += 64)
        wds[chbase + i / 9][i % 9] = w_dw[(chbase + i / 9) * 9 + i % 9];

    // A-frags (w_in split hi/lo): t1 och = 32w+o*16+l15; t2 och = 128 + same.
    uint4v A1h[2][2], A1l[2][2], A2h[2][2], A2l[2][2];
    #pragma unroll
    for (int o = 0; o < 2; ++o)
    #pragma unroll
    for (int kh = 0; kh < 2; ++kh) {
        const int ich = kh * 32 + l4 * 8;
        const float* wp1 = w_in + (chbase + o * 16 + l15) * 64 + ich;
        const float* wp2 = wp1 + 128 * 64;
        uint4v h1, l1, h2, l2;
        #pragma unroll
        for (int j = 0; j < 4; ++j) {
            float f0 = wp1[2*j], f1 = wp1[2*j+1];
            unsigned u0 = f2bf(f0), u1 = f2bf(f1);
            h1[j] = (u1 << 16) | u0;
            l1[j] = (f2bf(f1 - bf2f(u1)) << 16) | f2bf(f0 - bf2f(u0));
            float g0 = wp2[2*j], g1 = wp2[2*j+1];
            unsigned v0 = f2bf(g0), v1 = f2bf(g1);
            h2[j] = (v1 << 16) | v0;
            l2[j] = (f2bf(g1 - bf2f(v1)) << 16) | f2bf(g0 - bf2f(v0));
        }
        A1h[o][kh] = h1; A1l[o][kh] = l1;
        A2h[o][kh] = h2; A2l[o][kh] = l2;
    }

    const size_t xbase = ((size_t)b << 16) * 64;   // shorts

    // ---- phase 1: t1 (dw-conv input) over halo px -> LDS bf16
    #pragma unroll 2
    for (int ht = 0; ht < 22; ++ht) {
        const int p = ht * 16 + l15;              // flat halo idx (pad to 352)
        const unsigned row = (unsigned)p / 34u;
        const int col = p - (int)row * 34;
        const int gy = y0 - 1 + (int)row;
        const int gx = x0 - 1 + col;
        const bool inb = (p < 340) && ((unsigned)gy < 256u) && ((unsigned)gx < 256u);
        uint4v bh0 = {0,0,0,0}, bh1 = {0,0,0,0}, bl0 = {0,0,0,0}, bl1 = {0,0,0,0};
        if (inb) {
            const size_t off = xbase + ((size_t)(gy * 256 + gx)) * 64 + l4 * 8;
            bh0 = *(const uint4v*)(xh + off);
            bh1 = *(const uint4v*)(xh + off + 32);
            bl0 = *(const uint4v*)(xl + off);
            bl1 = *(const uint4v*)(xl + off + 32);
        }
        #pragma unroll
        for (int o = 0; o < 2; ++o) {
            f32x4 a = {0.f, 0.f, 0.f, 0.f};
            a = __builtin_amdgcn_mfma_f32_16x16x32_bf16(asbf(A1h[o][0]), asbf(bh0), a, 0,0,0);
            a = __builtin_amdgcn_mfma_f32_16x16x32_bf16(asbf(A1h[o][1]), asbf(bh1), a, 0,0,0);
            a = __builtin_amdgcn_mfma_f32_16x16x32_bf16(asbf(A1h[o][0]), asbf(bl0), a, 0,0,0);
            a = __builtin_amdgcn_mfma_f32_16x16x32_bf16(asbf(A1h[o][1]), asbf(bl1), a, 0,0,0);
            a = __builtin_amdgcn_mfma_f32_16x16x32_bf16(asbf(A1l[o][0]), asbf(bh0), a, 0,0,0);
            a = __builtin_amdgcn_mfma_f32_16x16x32_bf16(asbf(A1l[o][1]), asbf(bh1), a, 0,0,0);
            if (p < 340) {
                const int chb = chbase + o * 16 + l4 * 4;
                #pragma unroll
                for (int r = 0; r < 4; ++r)
                    t1s[(chb + r) * T1STR + p] = (unsigned short)f2bf(a[r]);
            }
        }
    }

    // ---- phase 2: t2 (gate) over center px -> LDS bf16
    #pragma unroll 2
    for (int ct = 0; ct < 16; ++ct) {
        const int p = ct * 16 + l15;
        const int y = p >> 5, x = p & 31;
        const size_t off = xbase + ((size_t)((y0 + y) * 256 + x0 + x)) * 64 + l4 * 8;
        const uint4v bh0 = *(const uint4v*)(xh + off);
        const uint4v bh1 = *(const uint4v*)(xh + off + 32);
        const uint4v bl0 = *(const uint4v*)(xl + off);
        const uint4v bl1 = *(const uint4v*)(xl + off + 32);
        #pragma unroll
        for (int o = 0; o < 2; ++o) {
            f32x4 a = {0.f, 0.f, 0.f, 0.f};
            a = __builtin_amdgcn_mfma_f32_16x16x32_bf16(asbf(A2h[o][0]), asbf(bh0), a, 0,0,0);
            a = __builtin_amdgcn_mfma_f32_16x16x32_bf16(asbf(A2h[o][1]), asbf(bh1), a, 0,0,0);
            a = __builtin_amdgcn_mfma_f32_16x16x32_bf16(asbf(A2h[o][0]), asbf(bl0), a, 0,0,0);
            a = __builtin_amdgcn_mfma_f32_16x16x32_bf16(asbf(A2h[o][1]), asbf(bl1), a, 0,0,0);
            a = __builtin_amdgcn_mfma_f32_16x16x32_bf16(asbf(A2l[o][0]), asbf(bh0), a, 0,0,0);
            a = __builtin_amdgcn_mfma_f32_16x16x32_bf16(asbf(A2l[o][1]), asbf(bh1), a, 0,0,0);
            const int chb = chbase + o * 16 + l4 * 4;
            #pragma unroll
            for (int r = 0; r < 4; ++r)
                t2s[(chb + r) * T2STR + p] = (unsigned short)f2bf(a[r]);
        }
    }

    // ---- phase 3: dw 3x3 + gate (wave-private channels; no barrier needed)
    float sq[2][4] = {{0.f,0.f,0.f,0.f},{0.f,0.f,0.f,0.f}};
    for (int ct = 0; ct < 16; ++ct) {
        const int p = ct * 16 + l15;
        const int y = p >> 5, x = p & 31;
        const int hb = y * 34 + x;    // center (y,x) <-> halo (y+1,x+1); taps +0..+70
        #pragma unroll
        for (int o = 0; o < 2; ++o) {
            const int chb = chbase + o * 16 + l4 * 4;
            #pragma unroll
            for (int r = 0; r < 4; ++r) {
                const int ch = chb + r;
                const unsigned short* tp = &t1s[ch * T1STR + hb];
                const float* wd = wds[ch];
                const float s = wd[0]*bf2f(tp[0])  + wd[1]*bf2f(tp[1])  + wd[2]*bf2f(tp[2])
                              + wd[3]*bf2f(tp[34]) + wd[4]*bf2f(tp[35]) + wd[5]*bf2f(tp[36])
                              + wd[6]*bf2f(tp[68]) + wd[7]*bf2f(tp[69]) + wd[8]*bf2f(tp[70]);
                const float t2f = bf2f(t2s[ch * T2STR + p]);
                const float q = s * t2f;
                sq[o][r] += q * q;
                const unsigned hq = f2bf(q);
                t2s[ch * T2STR + p] = (unsigned short)hq;   // qv bf16 for G phase
                if (wv >= 2) {                              // v half -> global packed
                    const unsigned lq = f2bf(q - bf2f(hq));
                    vpk[(((size_t)b * 64 + (ch - 64)) << 16)
                        + (y0 + y) * 256 + x0 + x] = (hq << 16) | lq;
                }
            }
        }
    }

    __syncthreads();   // the only barrier: qv complete across waves

    // ---- phase 4: G-partial = q.v^T over this tile (K=256 px)
    f32x4 g[4];
    #pragma unroll
    for (int dt = 0; dt < 4; ++dt) { f32x4 z = {0.f,0.f,0.f,0.f}; g[dt] = z; }
    #pragma unroll
    for (int ks = 0; ks < 8; ++ks) {
        const int k0 = ks * 32 + l4 * 8;
        const short8 A = asbf(*(const uint4v*)&t2s[(16 * wv + l15) * T2STR + k0]);
        #pragma unroll
        for (int dt = 0; dt < 4; ++dt) {
            const short8 Bf = asbf(*(const uint4v*)&t2s[(64 + dt * 16 + l15) * T2STR + k0]);
            g[dt] = __builtin_amdgcn_mfma_f32_16x16x32_bf16(A, Bf, g[dt], 0, 0, 0);
        }
    }
    float* gp = Gpart + ((size_t)blk << 12);
    const int c = 16 * wv + l4 * 4;
    #pragma unroll
    for (int dt = 0; dt < 4; ++dt)
    #pragma unroll
    for (int r = 0; r < 4; ++r)
        gp[(c + r) * 64 + dt * 16 + l15] = g[dt][r];

    // ---- norms: reduce over the 16-lane px group, one atomic per (ch)
    #pragma unroll
    for (int o = 0; o < 2; ++o)
    #pragma unroll
    for (int r = 0; r < 4; ++r) {
        float vs = sq[o][r];
        vs += __shfl_xor(vs, 1);
        vs += __shfl_xor(vs, 2);
        vs += __shfl_xor(vs, 4);
        vs += __shfl_xor(vs, 8);
        if (l15 == 0) {
            const int ch = chbase + o * 16 + l4 * 4 + r;
            if (ch < 64) atomicAdd(&sqq[b * 64 + ch], vs);
            else         atomicAdd(&sqv[b * 64 + ch - 64], vs);
        }
    }
}

// ---------------------------------------------------------------------------
// kR: reduce 256 G partials per batch. Grid: 64 blocks x 256 thr.
// ---------------------------------------------------------------------------
__global__ __launch_bounds__(256)
void kR_red(const float* __restrict__ Gpart, float* __restrict__ Gred)
{
    const int gid = blockIdx.x * 256 + threadIdx.x;   // 16384
    const int b = gid >> 12, i = gid & 4095;
    float s = 0.f;
    #pragma unroll 8
    for (int p = 0; p < 256; ++p)
        s += Gpart[((((size_t)b * 256) + p) << 12) + i];
    Gred[((size_t)b << 12) + i] = s;
}

// ---------------------------------------------------------------------------
// kD: per batch: norms, softmax(G*temp/(|q||v|)), M = w_out @ attn
// ---------------------------------------------------------------------------
__global__ __launch_bounds__(256)
void kD_softmax(const float* __restrict__ Gred, const float* __restrict__ sqq,
                const float* __restrict__ sqv, const float* __restrict__ temp,
                const float* __restrict__ w_out, float* __restrict__ M)
{
    __shared__ float attn_s[64][65];
    __shared__ float wo_s[64][65];
    __shared__ float nv_s[64];
    const int b = blockIdx.x, tid = threadIdx.x;

    for (int i = tid; i < 4096; i += 256) {
        int o = i >> 6, c = i & 63;
        wo_s[o][c] = w_out[i];
    }
    if (tid < 64) nv_s[tid] = fmaxf(sqrtf(sqv[b * 64 + tid]), EPSF);
    __syncthreads();

    if (tid < 64) {
        const int c = tid;
        const float nq = fmaxf(sqrtf(sqq[b * 64 + c]), EPSF);
        const float scale = temp[0] / nq;
        float m = -1e30f;
        for (int d = 0; d < 64; ++d) {
            float s = Gred[b * 4096 + c * 64 + d] / nv_s[d] * scale;
            attn_s[c][d] = s;
            m = fmaxf(m, s);
        }
        float sum = 0.f;
        for (int d = 0; d < 64; ++d) {
            float e = expf(attn_s[c][d] - m);
            attn_s[c][d] = e;
            sum += e;
        }
        const float inv = 1.0f / sum;
        for (int d = 0; d < 64; ++d) attn_s[c][d] *= inv;
    }
    __syncthreads();

    const int o = tid & 63, dq = tid >> 6;
    float acc[16];
    #pragma unroll
    for (int j = 0; j < 16; ++j) acc[j] = 0.f;
    for (int c = 0; c < 64; ++c) {
        const float wv = wo_s[o][c];
        #pragma unroll
        for (int j = 0; j < 16; ++j) acc[j] += wv * attn_s[c][dq * 16 + j];
    }
    #pragma unroll
    for (int j = 0; j < 16; ++j) M[b * 4096 + o * 64 + dq * 16 + j] = acc[j];
}

// ---------------------------------------------------------------------------
// kE: out = M @ v, in-place over d_out (v stored packed hi<<16|lo).
// ---------------------------------------------------------------------------
__global__ __launch_bounds__(256)
void kE_out(const float* __restrict__ M, float* vout)
{
    __shared__ __attribute__((aligned(16))) float M_s[64][64];
    const int blk = blockIdx.x;
    const int b = blk >> 7, nb = blk & 127;
    const int tid = threadIdx.x;
    for (int i = tid; i < 4096; i += 256) M_s[i >> 6][i & 63] = M[b * 4096 + i];
    __syncthreads();

    const int n0 = nb * 512 + tid;
    float* vb = vout + ((size_t)b << 22);

    float vr0[64], vr1[64];
    #pragma unroll
    for (int d = 0; d < 64; ++d) {
        const unsigned u0 = __float_as_uint(vb[((size_t)d << 16) + n0]);
        const unsigned u1 = __float_as_uint(vb[((size_t)d << 16) + n0 + 256]);
        vr0[d] = __uint_as_float(u0 & 0xFFFF0000u) + __uint_as_float(u0 << 16);
        vr1[d] = __uint_as_float(u1 & 0xFFFF0000u) + __uint_as_float(u1 << 16);
    }
    for (int o = 0; o < 64; ++o) {
        float a0 = 0.f, a1 = 0.f;
        #pragma unroll
        for (int dq = 0; dq < 16; ++dq) {
            const float4 m4 = *(const float4*)(&M_s[o][dq * 4]);
            a0 += m4.x * vr0[dq*4+0]; a1 += m4.x * vr1[dq*4+0];
            a0 += m4.y * vr0[dq*4+1]; a1 += m4.y * vr1[dq*4+1];
            a0 += m4.z * vr0[dq*4+2]; a1 += m4.z * vr1[dq*4+2];
            a0 += m4.w * vr0[dq*4+3]; a1 += m4.w * vr1[dq*4+3];
        }
        vb[((size_t)o << 16) + n0] = a0;
        vb[((size_t)o << 16) + n0 + 256] = a1;
    }
}

// ===========================================================================
// FALLBACK PATH — round-1 kernels (used when ws_size is too small)
// ===========================================================================
__global__ __launch_bounds__(NT1)
void k1_fused(const float* __restrict__ x, const float* __restrict__ w_in,
              const float* __restrict__ w_dw, float* __restrict__ v_out,
              float* __restrict__ Gacc, float* __restrict__ sqq,
              float* __restrict__ sqv)
{
    __shared__ __attribute__((aligned(16))) float wT[64][256];
    __shared__ __attribute__((aligned(16))) float wdw_s[128][11];
    __shared__ __attribute__((aligned(16))) float xs[64][104];
    __shared__ __attribute__((aligned(16))) float t1s[64][105];
    __shared__ __attribute__((aligned(16))) float qvs[64][132];

    const int tid = threadIdx.x;
    const int blk = blockIdx.x;
    const int b = blk >> 6;
    const int bslot = blk & 63;

    for (int i = tid; i < 256 * 64; i += NT1) {
        int ch = i >> 6, c = i & 63;
        wT[c][ch] = w_in[i];
    }
    for (int i = tid; i < 128 * 9; i += NT1) {
        int ch = i / 9, k = i - ch * 9;
        wdw_s[ch][k] = w_dw[i];
    }

    const int gc0 = (tid >> 4) * 2;
    const int gd0 = (tid & 15) * 4;
    float g00 = 0, g01 = 0, g02 = 0, g03 = 0;
    float g10 = 0, g11 = 0, g12 = 0, g13 = 0;
    float sqreg = 0.f;

    const float* xb = x + ((size_t)b << 22);

    for (int tIdx = 0; tIdx < 16; ++tIdx) {
        const int tile = bslot + (tIdx << 6);
        const int ty0 = (tile >> 5) << 3;
        const int tx0 = (tile & 31) << 3;

        __syncthreads();

        for (int i = tid; i < 64 * 104; i += NT1) {
            int c = i / 104;
            int col = i - c * 104;
            float val = 0.f;
            if (col < 100) {
                int py = col / 10;
                int px = col - py * 10;
                int gy = ty0 - 1 + py;
                int gx = tx0 - 1 + px;
                if ((unsigned)gy < 256u && (unsigned)gx < 256u)
                    val = xb[((size_t)c << 16) + (gy << 8) + gx];
            }
            xs[c][col] = val;
        }
        __syncthreads();

        for (int h = 0; h < 2; ++h) {
            for (int it = tid; it < 672; it += NT1) {
                if (it < 416) {
                    const int chq = it / 26;
                    const int pq = it - chq * 26;
                    const int ch0 = (h << 6) + (chq << 2);
                    const int p0 = pq << 2;
                    float a00=0,a01=0,a02=0,a03=0, a10=0,a11=0,a12=0,a13=0;
                    float a20=0,a21=0,a22=0,a23=0, a30=0,a31=0,a32=0,a33=0;
                    #pragma unroll 4
                    for (int c = 0; c < 64; ++c) {
                        const float4 wv = *(const float4*)(&wT[c][ch0]);
                        const float4 xv = *(const float4*)(&xs[c][p0]);
                        a00 += wv.x*xv.x; a01 += wv.x*xv.y; a02 += wv.x*xv.z; a03 += wv.x*xv.w;
                        a10 += wv.y*xv.x; a11 += wv.y*xv.y; a12 += wv.y*xv.z; a13 += wv.y*xv.w;
                        a20 += wv.z*xv.x; a21 += wv.z*xv.y; a22 += wv.z*xv.z; a23 += wv.z*xv.w;
                        a30 += wv.w*xv.x; a31 += wv.w*xv.y; a32 += wv.w*xv.z; a33 += wv.w*xv.w;
                    }
                    const int lc = chq << 2;
                    t1s[lc+0][p0+0]=a00; t1s[lc+0][p0+1]=a01; t1s[lc+0][p0+2]=a02; t1s[lc+0][p0+3]=a03;
                    t1s[lc+1][p0+0]=a10; t1s[lc+1][p0+1]=a11; t1s[lc+1][p0+2]=a12; t1s[lc+1][p0+3]=a13;
                    t1s[lc+2][p0+0]=a20; t1s[lc+2][p0+1]=a21; t1s[lc+2][p0+2]=a22; t1s[lc+2][p0+3]=a23;
                    t1s[lc+3][p0+0]=a30; t1s[lc+3][p0+1]=a31; t1s[lc+3][p0+2]=a32; t1s[lc+3][p0+3]=a33;
                } else {
                    const int j = it - 416;
                    const int chq = j >> 4;
                    const int pq = j & 15;
                    const int ch0 = 128 + (h << 6) + (chq << 2);
                    const int p0 = pq << 2;
                    const int y = p0 >> 3, xc = p0 & 7;
                    const int hp0 = (y + 1) * 10 + xc + 1;
                    float a00=0,a01=0,a02=0,a03=0, a10=0,a11=0,a12=0,a13=0;
                    float a20=0,a21=0,a22=0,a23=0, a30=0,a31=0,a32=0,a33=0;
                    #pragma unroll 4
                    for (int c = 0; c < 64; ++c) {
                        const float4 wv = *(const float4*)(&wT[c][ch0]);
                        const float x0 = xs[c][hp0+0], x1 = xs[c][hp0+1];
                        const float x2 = xs[c][hp0+2], x3 = xs[c][hp0+3];
                        a00 += wv.x*x0; a01 += wv.x*x1; a02 += wv.x*x2; a03 += wv.x*x3;
                        a10 += wv.y*x0; a11 += wv.y*x1; a12 += wv.y*x2; a13 += wv.y*x3;
                        a20 += wv.z*x0; a21 += wv.z*x1; a22 += wv.z*x2; a23 += wv.z*x3;
                        a30 += wv.w*x0; a31 += wv.w*x1; a32 += wv.w*x2; a33 += wv.w*x3;
                    }
                    const int qc = (h << 6) + (chq << 2);
                    *(float4*)(&qvs[p0+0][qc]) = make_float4(a00, a10, a20, a30);
                    *(float4*)(&qvs[p0+1][qc]) = make_float4(a01, a11, a21, a31);
                    *(float4*)(&qvs[p0+2][qc]) = make_float4(a02, a12, a22, a32);
                    *(float4*)(&qvs[p0+3][qc]) = make_float4(a03, a13, a23, a33);
                }
            }
            __syncthreads();
            for (int it = tid; it < 4096; it += NT1) {
                const int ch = it & 63;
                const int p = it >> 6;
                const int y = p >> 3, xc = p & 7;
                const int base = y * 10 + xc;
                const float* wd = &wdw_s[(h << 6) + ch][0];
                float s = wd[0]*t1s[ch][base+ 0] + wd[1]*t1s[ch][base+ 1] + wd[2]*t1s[ch][base+ 2]
                        + wd[3]*t1s[ch][base+10] + wd[4]*t1s[ch][base+11] + wd[5]*t1s[ch][base+12]
                        + wd[6]*t1s[ch][base+20] + wd[7]*t1s[ch][base+21] + wd[8]*t1s[ch][base+22];
                const int qc = (h << 6) + ch;
                qvs[p][qc] = s * qvs[p][qc];
            }
            __syncthreads();
        }

        #pragma unroll 4
        for (int p = 0; p < 64; ++p) {
            const float2 q2 = *(const float2*)(&qvs[p][gc0]);
            const float4 v4 = *(const float4*)(&qvs[p][64 + gd0]);
            g00 += q2.x*v4.x; g01 += q2.x*v4.y; g02 += q2.x*v4.z; g03 += q2.x*v4.w;
            g10 += q2.y*v4.x; g11 += q2.y*v4.y; g12 += q2.y*v4.z; g13 += q2.y*v4.w;
        }
        if (tid < 128) {
            #pragma unroll 8
            for (int p = 0; p < 64; ++p) {
                const float val = qvs[p][tid];
                sqreg += val * val;
            }
        }
        for (int it = tid; it < 4096; it += NT1) {
            const int p = it & 63;
            const int d = it >> 6;
            const int gy = ty0 + (p >> 3), gx = tx0 + (p & 7);
            v_out[((size_t)(b * 64 + d) << 16) + (gy << 8) + gx] = qvs[p][64 + d];
        }
    }

    const int gb = b * 4096;
    atomicAdd(&Gacc[gb + (gc0 + 0) * 64 + gd0 + 0], g00);
    atomicAdd(&Gacc[gb + (gc0 + 0) * 64 + gd0 + 1], g01);
    atomicAdd(&Gacc[gb + (gc0 + 0) * 64 + gd0 + 2], g02);
    atomicAdd(&Gacc[gb + (gc0 + 0) * 64 + gd0 + 3], g03);
    atomicAdd(&Gacc[gb + (gc0 + 1) * 64 + gd0 + 0], g10);
    atomicAdd(&Gacc[gb + (gc0 + 1) * 64 + gd0 + 1], g11);
    atomicAdd(&Gacc[gb + (gc0 + 1) * 64 + gd0 + 2], g12);
    atomicAdd(&Gacc[gb + (gc0 + 1) * 64 + gd0 + 3], g13);
    if (tid < 64)       atomicAdd(&sqq[b * 64 + tid], sqreg);
    else if (tid < 128) atomicAdd(&sqv[b * 64 + tid - 64], sqreg);
}

__global__ __launch_bounds__(256)
void k3_out(const float* __restrict__ M, const float* v, float* out)
{
    __shared__ __attribute__((aligned(16))) float M_s[64][64];
    const int blk = blockIdx.x;
    const int b = blk >> 7;
    const int nb = blk & 127;
    const int tid = threadIdx.x;
    for (int i = tid; i < 4096; i += 256) M_s[i >> 6][i & 63] = M[b * 4096 + i];
    __syncthreads();

    const int n0 = nb * 512 + tid;
    const float* vb = v + ((size_t)b << 22);
    float* ob = out + ((size_t)b << 22);

    float vr0[64], vr1[64];
    #pragma unroll
    for (int d = 0; d < 64; ++d) {
        vr0[d] = vb[((size_t)d << 16) + n0];
        vr1[d] = vb[((size_t)d << 16) + n0 + 256];
    }
    for (int o = 0; o < 64; ++o) {
        float a0 = 0.f, a1 = 0.f;
        #pragma unroll
        for (int dq = 0; dq < 16; ++dq) {
            const float4 m4 = *(const float4*)(&M_s[o][dq * 4]);
            a0 += m4.x * vr0[dq*4+0]; a1 += m4.x * vr1[dq*4+0];
            a0 += m4.y * vr0[dq*4+1]; a1 += m4.y * vr1[dq*4+1];
            a0 += m4.z * vr0[dq*4+2]; a1 += m4.z * vr1[dq*4+2];
            a0 += m4.w * vr0[dq*4+3]; a1 += m4.w * vr1[dq*4+3];
        }
        ob[((size_t)o << 16) + n0] = a0;
        ob[((size_t)o << 16) + n0 + 256] = a1;
    }
}

// ===========================================================================
extern "C" void kernel_launch(void* const* d_in, const int* in_sizes, int n_in,
                              void* d_out, int out_size, void* d_ws, size_t ws_size,
                              hipStream_t stream)
{
    (void)in_sizes; (void)n_in; (void)out_size;
    const float* x     = (const float*)d_in[0];
    const float* w_in  = (const float*)d_in[1];
    const float* w_dw  = (const float*)d_in[2];
    const float* w_out = (const float*)d_in[3];
    const float* temp  = (const float*)d_in[4];
    float* out = (float*)d_out;

    // fast-path workspace layout (bytes)
    const size_t OFF_XH    = 0;                   // 33554432
    const size_t OFF_XL    = 33554432;            // 33554432
    const size_t OFF_GPART = 67108864;            // 16777216 (1024 blocks x 16KB)
    const size_t OFF_GRED  = 83886080;            // 65536
    const size_t OFF_SQQ   = 83951616;            // 1024
    const size_t OFF_SQV   = 83952640;            // 1024
    const size_t OFF_M     = 83953664;            // 65536
    const size_t NEED      = 84019200;            // ~80.1 MiB

    if (ws_size >= NEED) {
        char* ws = (char*)d_ws;
        unsigned short* xh  = (unsigned short*)(ws + OFF_XH);
        unsigned short* xl  = (unsigned short*)(ws + OFF_XL);
        float* Gpart = (float*)(ws + OFF_GPART);
        float* Gred  = (float*)(ws + OFF_GRED);
        float* sqq   = (float*)(ws + OFF_SQQ);
        float* sqv   = (float*)(ws + OFF_SQV);
        float* Mws   = (float*)(ws + OFF_M);

        hipMemsetAsync((void*)sqq, 0, 2048, stream);
        hipLaunchKernelGGL(kA_split, dim3(1024), dim3(256), 0, stream, x, xh, xl);
        hipLaunchKernelGGL(kF_fused, dim3(1024), dim3(256), 0, stream,
                           xh, xl, w_in, w_dw, (unsigned*)d_out, Gpart, sqq, sqv);
        hipLaunchKernelGGL(kR_red, dim3(64), dim3(256), 0, stream, Gpart, Gred);
        hipLaunchKernelGGL(kD_softmax, dim3(4), dim3(256), 0, stream,
                           Gred, sqq, sqv, temp, w_out, Mws);
        hipLaunchKernelGGL(kE_out, dim3(512), dim3(256), 0, stream, Mws, out);
    } else {
        // fallback: round-1 path (~133 KiB ws)
        float* Gacc = (float*)d_ws;
        float* sqq  = Gacc + 16384;
        float* sqv  = sqq + 256;
        float* Mws  = sqv + 256;
        hipMemsetAsync((void*)Gacc, 0, (16384 + 512) * sizeof(float), stream);
        hipLaunchKernelGGL(k1_fused, dim3(256), dim3(NT1), 0, stream,
                           x, w_in, w_dw, out, Gacc, sqq, sqv);
        hipLaunchKernelGGL(kD_softmax, dim3(4), dim3(256), 0, stream,
                           Gacc, sqq, sqv, temp, w_out, Mws);
        hipLaunchKernelGGL(k3_out, dim3(512), dim3(256), 0, stream,
                           Mws, out, out);
    }
}

// Round 5
// 446.533 us; speedup vs baseline: 1.1839x; 1.1839x over previous
//
#include <hip/hip_runtime.h>

#define EPSF 1e-12f
#define NT1 512

typedef __attribute__((ext_vector_type(8))) short short8;     // MFMA bf16 A/B frag
typedef __attribute__((ext_vector_type(4))) float f32x4;      // MFMA C/D frag
typedef __attribute__((ext_vector_type(4))) unsigned int uint4v;
typedef __attribute__((ext_vector_type(2))) unsigned int uint2v;

__device__ __forceinline__ unsigned f2bf(float f) {
    unsigned u = __float_as_uint(f);
    return (u + 0x7FFFu + ((u >> 16) & 1u)) >> 16;
}
__device__ __forceinline__ float bf2f(unsigned h) { return __uint_as_float(h << 16); }
__device__ __forceinline__ short8 asbf(uint4v u) { return __builtin_bit_cast(short8, u); }

// ===========================================================================
// FAST PATH
// ===========================================================================

// ---------------------------------------------------------------------------
// kQ: per (batch, half, 8x32-tile): t = W@x (MFMA, split-bf16 from fp32 in
// registers) -> LDS -> dw 3x3 + gate -> qh (bf16) or vpk (packed u32) + norms.
// 64 channels/block. Wave owns 16 channels end-to-end: NO barriers.
// LDS: t1s 64x360 + t2s 64x264 shorts = 79872 B -> 2 blocks/CU (8 waves/CU).
// Grid: 2048 blocks ([b:2][tile:8][half:1]) x 256 thr.
// ---------------------------------------------------------------------------
__global__ __launch_bounds__(256, 2)
void kQ_half(const float* __restrict__ x, const float* __restrict__ w_in,
             const float* __restrict__ w_dw, unsigned short* __restrict__ qh,
             unsigned* __restrict__ vpk, float* __restrict__ sqq,
             float* __restrict__ sqv)
{
    __shared__ unsigned short t1s[64 * 360];   // [ch][halo row*36 + col(0..33)]
    __shared__ unsigned short t2s[64 * 264];   // [ch][center px 0..255]

    const int tid = threadIdx.x;
    const int wv = tid >> 6, lane = tid & 63;
    const int l15 = lane & 15, l4 = lane >> 4;

    const int blk = blockIdx.x;
    const int half = blk & 1;
    const int tile = (blk >> 1) & 255;
    const int b = blk >> 9;
    const int y0 = (tile >> 3) << 3;      // 32 row-tiles of 8
    const int x0t = (tile & 7) << 5;      // 8 col-tiles of 32

    // A-frags: w_in rows. t1-och = half*64 + wv*16 + l15 ; t2-och = 128 + same.
    uint4v A1h[2], A1l[2], A2h[2], A2l[2];
    #pragma unroll
    for (int kh = 0; kh < 2; ++kh) {
        const float* wp1 = w_in + (half * 64 + wv * 16 + l15) * 64 + kh * 32 + l4 * 8;
        const float* wp2 = wp1 + 128 * 64;
        uint4v h1, l1, h2, l2;
        #pragma unroll
        for (int j = 0; j < 4; ++j) {
            float f0 = wp1[2*j], f1 = wp1[2*j+1];
            unsigned u0 = f2bf(f0), u1 = f2bf(f1);
            h1[j] = (u1 << 16) | u0;
            l1[j] = (f2bf(f1 - bf2f(u1)) << 16) | f2bf(f0 - bf2f(u0));
            float g0 = wp2[2*j], g1 = wp2[2*j+1];
            unsigned v0 = f2bf(g0), v1 = f2bf(g1);
            h2[j] = (v1 << 16) | v0;
            l2[j] = (f2bf(g1 - bf2f(v1)) << 16) | f2bf(g0 - bf2f(v0));
        }
        A1h[kh] = h1; A1l[kh] = l1;
        A2h[kh] = h2; A2l[kh] = l2;
    }

    const float* xb = x + ((size_t)b << 22);

    // ---- phase 1+2 merged: t1 over halo px, t2 over (masked) center px
    #pragma unroll 2
    for (int ht = 0; ht < 22; ++ht) {
        const int p = ht * 16 + l15;               // flat halo idx, valid < 340
        const unsigned row = (unsigned)p / 34u;
        const int col = p - (int)row * 34;
        const int gy = y0 - 1 + (int)row;
        const int gx = x0t - 1 + col;
        const bool inb = (p < 340) && ((unsigned)gy < 256u) && ((unsigned)gx < 256u);

        float xv0[8], xv1[8];
        #pragma unroll
        for (int j = 0; j < 8; ++j) { xv0[j] = 0.f; xv1[j] = 0.f; }
        if (inb) {
            const float* bp = xb + (size_t)(gy * 256 + gx);
            #pragma unroll
            for (int j = 0; j < 8; ++j) {
                xv0[j] = bp[(size_t)(l4 * 8 + j) << 16];
                xv1[j] = bp[(size_t)(32 + l4 * 8 + j) << 16];
            }
        }
        uint4v bh0, bl0, bh1, bl1;
        #pragma unroll
        for (int j = 0; j < 4; ++j) {
            unsigned h0 = f2bf(xv0[2*j]), h1 = f2bf(xv0[2*j+1]);
            bh0[j] = (h1 << 16) | h0;
            bl0[j] = (f2bf(xv0[2*j+1] - bf2f(h1)) << 16) | f2bf(xv0[2*j] - bf2f(h0));
            unsigned g0 = f2bf(xv1[2*j]), g1 = f2bf(xv1[2*j+1]);
            bh1[j] = (g1 << 16) | g0;
            bl1[j] = (f2bf(xv1[2*j+1] - bf2f(g1)) << 16) | f2bf(xv1[2*j] - bf2f(g0));
        }
        const short8 Bh0 = asbf(bh0), Bh1 = asbf(bh1);
        const short8 Bl0 = asbf(bl0), Bl1 = asbf(bl1);

        f32x4 a1 = {0.f, 0.f, 0.f, 0.f};
        a1 = __builtin_amdgcn_mfma_f32_16x16x32_bf16(asbf(A1h[0]), Bh0, a1, 0,0,0);
        a1 = __builtin_amdgcn_mfma_f32_16x16x32_bf16(asbf(A1h[1]), Bh1, a1, 0,0,0);
        a1 = __builtin_amdgcn_mfma_f32_16x16x32_bf16(asbf(A1h[0]), Bl0, a1, 0,0,0);
        a1 = __builtin_amdgcn_mfma_f32_16x16x32_bf16(asbf(A1h[1]), Bl1, a1, 0,0,0);
        a1 = __builtin_amdgcn_mfma_f32_16x16x32_bf16(asbf(A1l[0]), Bh0, a1, 0,0,0);
        a1 = __builtin_amdgcn_mfma_f32_16x16x32_bf16(asbf(A1l[1]), Bh1, a1, 0,0,0);

        f32x4 a2 = {0.f, 0.f, 0.f, 0.f};
        a2 = __builtin_amdgcn_mfma_f32_16x16x32_bf16(asbf(A2h[0]), Bh0, a2, 0,0,0);
        a2 = __builtin_amdgcn_mfma_f32_16x16x32_bf16(asbf(A2h[1]), Bh1, a2, 0,0,0);
        a2 = __builtin_amdgcn_mfma_f32_16x16x32_bf16(asbf(A2h[0]), Bl0, a2, 0,0,0);
        a2 = __builtin_amdgcn_mfma_f32_16x16x32_bf16(asbf(A2h[1]), Bl1, a2, 0,0,0);
        a2 = __builtin_amdgcn_mfma_f32_16x16x32_bf16(asbf(A2l[0]), Bh0, a2, 0,0,0);
        a2 = __builtin_amdgcn_mfma_f32_16x16x32_bf16(asbf(A2l[1]), Bh1, a2, 0,0,0);

        if (p < 340) {
            const int chb = wv * 16 + l4 * 4;
            #pragma unroll
            for (int r = 0; r < 4; ++r)
                t1s[(chb + r) * 360 + (int)row * 36 + col] = (unsigned short)f2bf(a1[r]);
        }
        if (row >= 1u && row <= 8u && col >= 1 && col <= 32) {
            const int cpx = ((int)row - 1) * 32 + (col - 1);
            const int chb = wv * 16 + l4 * 4;
            #pragma unroll
            for (int r = 0; r < 4; ++r)
                t2s[(chb + r) * 264 + cpx] = (unsigned short)f2bf(a2[r]);
        }
    }
    // wave-private channels: same-wave LDS write->read ordering is automatic.

    // ---- phase 3: dw 3x3 + gate, 8-px strips, vectorized LDS reads
    for (int it = 0; it < 8; ++it) {
        const int ch = wv * 16 + it * 2 + (lane >> 5);
        const int strip = lane & 31;
        const int row = strip >> 2, xs0 = (strip & 3) << 3;
        const float* wd = w_dw + (half * 64 + ch) * 9;
        const float w0 = wd[0], w1 = wd[1], w2 = wd[2];
        const float w3 = wd[3], w4 = wd[4], w5 = wd[5];
        const float w6 = wd[6], w7 = wd[7], w8 = wd[8];

        float win[3][10];
        #pragma unroll
        for (int r3 = 0; r3 < 3; ++r3) {
            const unsigned short* tp = &t1s[ch * 360 + (row + r3) * 36 + xs0];
            const uint2v ua = *(const uint2v*)tp;        // shorts 0..3
            const uint2v ub = *(const uint2v*)(tp + 4);  // shorts 4..7
            const unsigned uc = *(const unsigned*)(tp + 8); // shorts 8..9
            win[r3][0] = bf2f(ua[0] & 0xFFFFu); win[r3][1] = bf2f(ua[0] >> 16);
            win[r3][2] = bf2f(ua[1] & 0xFFFFu); win[r3][3] = bf2f(ua[1] >> 16);
            win[r3][4] = bf2f(ub[0] & 0xFFFFu); win[r3][5] = bf2f(ub[0] >> 16);
            win[r3][6] = bf2f(ub[1] & 0xFFFFu); win[r3][7] = bf2f(ub[1] >> 16);
            win[r3][8] = bf2f(uc & 0xFFFFu);    win[r3][9] = bf2f(uc >> 16);
        }
        const uint4v gv = *(const uint4v*)&t2s[ch * 264 + row * 32 + xs0];

        float q8[8];
        float sq = 0.f;
        #pragma unroll
        for (int k = 0; k < 8; ++k) {
            const float dwv = w0*win[0][k] + w1*win[0][k+1] + w2*win[0][k+2]
                            + w3*win[1][k] + w4*win[1][k+1] + w5*win[1][k+2]
                            + w6*win[2][k] + w7*win[2][k+1] + w8*win[2][k+2];
            const unsigned tu = gv[k >> 1];
            const float t2f = bf2f((k & 1) ? (tu >> 16) : (tu & 0xFFFFu));
            const float q = dwv * t2f;
            q8[k] = q; sq += q * q;
        }
        const size_t plane = ((size_t)(b * 64 + ch)) << 16;
        const size_t opx = (size_t)(y0 + row) * 256 + x0t + xs0;
        if (half == 0) {
            uint4v hp;
            #pragma unroll
            for (int k = 0; k < 4; ++k)
                hp[k] = (f2bf(q8[2*k+1]) << 16) | f2bf(q8[2*k]);
            *(uint4v*)(qh + plane + opx) = hp;
        } else {
            uint4v pa, pb;
            #pragma unroll
            for (int k = 0; k < 4; ++k) {
                unsigned h = f2bf(q8[k]);
                pa[k] = (h << 16) | f2bf(q8[k] - bf2f(h));
                unsigned h2 = f2bf(q8[4+k]);
                pb[k] = (h2 << 16) | f2bf(q8[4+k] - bf2f(h2));
            }
            unsigned* dst = vpk + plane + opx;
            *(uint4v*)dst = pa; *(uint4v*)(dst + 4) = pb;
        }
        // norms: reduce the 32-lane group (covers the whole 256-px tile)
        sq += __shfl_xor(sq, 1);
        sq += __shfl_xor(sq, 2);
        sq += __shfl_xor(sq, 4);
        sq += __shfl_xor(sq, 8);
        sq += __shfl_xor(sq, 16);
        if ((lane & 31) == 0) {
            if (half == 0) atomicAdd(&sqq[b * 64 + ch], sq);
            else           atomicAdd(&sqv[b * 64 + ch], sq);
        }
    }
}

// ---------------------------------------------------------------------------
// kG: G = q @ v^T via MFMA (bf16-hi). Grid: 512 blocks x 256 thr (2/CU).
// wave = one 128-px stripe (512 stripes/batch), full 64x64 G-partial.
// ---------------------------------------------------------------------------
__global__ __launch_bounds__(256)
void kG_gemm(const unsigned short* __restrict__ qh, const unsigned* __restrict__ vpk,
             float* __restrict__ Gpart)
{
    const int blk = blockIdx.x, tid = threadIdx.x;
    const int b = blk >> 7, pblk = blk & 127;
    const int lane = tid & 63, wv = tid >> 6;
    const int l15 = lane & 15, l4 = lane >> 4;
    const int stripe = pblk * 4 + wv;       // 0..511
    const int px_base = stripe * 128;
    const unsigned short* qb = qh + ((size_t)b << 22);
    const unsigned* vb = vpk + ((size_t)b << 22);
    f32x4 acc[4][4];
    #pragma unroll
    for (int ct = 0; ct < 4; ++ct)
    #pragma unroll
    for (int dt = 0; dt < 4; ++dt) { f32x4 z = {0.f,0.f,0.f,0.f}; acc[ct][dt] = z; }

    for (int s = 0; s < 4; ++s) {
        const int kofs = px_base + s * 32 + l4 * 8;
        short8 A[4];
        #pragma unroll
        for (int ct = 0; ct < 4; ++ct)
            A[ct] = asbf(*(const uint4v*)(qb + (((size_t)(ct * 16 + l15)) << 16) + kofs));
        #pragma unroll
        for (int dt = 0; dt < 4; ++dt) {
            const unsigned* vp = vb + (((size_t)(dt * 16 + l15)) << 16) + kofs;
            const uint4v u0 = *(const uint4v*)vp;
            const uint4v u1 = *(const uint4v*)(vp + 4);
            uint4v bfv;
            bfv[0] = (u0[1] & 0xFFFF0000u) | (u0[0] >> 16);
            bfv[1] = (u0[3] & 0xFFFF0000u) | (u0[2] >> 16);
            bfv[2] = (u1[1] & 0xFFFF0000u) | (u1[0] >> 16);
            bfv[3] = (u1[3] & 0xFFFF0000u) | (u1[2] >> 16);
            const short8 Bf = asbf(bfv);
            #pragma unroll
            for (int ct = 0; ct < 4; ++ct)
                acc[ct][dt] = __builtin_amdgcn_mfma_f32_16x16x32_bf16(A[ct], Bf, acc[ct][dt], 0, 0, 0);
        }
    }
    float* gp = Gpart + (((size_t)b * 512 + stripe) << 12);
    #pragma unroll
    for (int ct = 0; ct < 4; ++ct)
    #pragma unroll
    for (int dt = 0; dt < 4; ++dt)
    #pragma unroll
    for (int r = 0; r < 4; ++r)
        gp[(ct * 16 + l4 * 4 + r) * 64 + dt * 16 + l15] = acc[ct][dt][r];
}

// ---------------------------------------------------------------------------
// kR: reduce 512 G partials per batch. Grid: 64 blocks x 256 thr.
// ---------------------------------------------------------------------------
__global__ __launch_bounds__(256)
void kR_red(const float* __restrict__ Gpart, float* __restrict__ Gred)
{
    const int gid = blockIdx.x * 256 + threadIdx.x;   // 16384
    const int b = gid >> 12, i = gid & 4095;
    float s = 0.f;
    #pragma unroll 8
    for (int p = 0; p < 512; ++p)
        s += Gpart[((((size_t)b * 512) + p) << 12) + i];
    Gred[((size_t)b << 12) + i] = s;
}

// ---------------------------------------------------------------------------
// kD: per batch: norms, softmax(G*temp/(|q||v|)), M = w_out @ attn
// ---------------------------------------------------------------------------
__global__ __launch_bounds__(256)
void kD_softmax(const float* __restrict__ Gred, const float* __restrict__ sqq,
                const float* __restrict__ sqv, const float* __restrict__ temp,
                const float* __restrict__ w_out, float* __restrict__ M)
{
    __shared__ float attn_s[64][65];
    __shared__ float wo_s[64][65];
    __shared__ float nv_s[64];
    const int b = blockIdx.x, tid = threadIdx.x;

    for (int i = tid; i < 4096; i += 256) {
        int o = i >> 6, c = i & 63;
        wo_s[o][c] = w_out[i];
    }
    if (tid < 64) nv_s[tid] = fmaxf(sqrtf(sqv[b * 64 + tid]), EPSF);
    __syncthreads();

    if (tid < 64) {
        const int c = tid;
        const float nq = fmaxf(sqrtf(sqq[b * 64 + c]), EPSF);
        const float scale = temp[0] / nq;
        float m = -1e30f;
        for (int d = 0; d < 64; ++d) {
            float s = Gred[b * 4096 + c * 64 + d] / nv_s[d] * scale;
            attn_s[c][d] = s;
            m = fmaxf(m, s);
        }
        float sum = 0.f;
        for (int d = 0; d < 64; ++d) {
            float e = expf(attn_s[c][d] - m);
            attn_s[c][d] = e;
            sum += e;
        }
        const float inv = 1.0f / sum;
        for (int d = 0; d < 64; ++d) attn_s[c][d] *= inv;
    }
    __syncthreads();

    const int o = tid & 63, dq = tid >> 6;
    float acc[16];
    #pragma unroll
    for (int j = 0; j < 16; ++j) acc[j] = 0.f;
    for (int c = 0; c < 64; ++c) {
        const float wv = wo_s[o][c];
        #pragma unroll
        for (int j = 0; j < 16; ++j) acc[j] += wv * attn_s[c][dq * 16 + j];
    }
    #pragma unroll
    for (int j = 0; j < 16; ++j) M[b * 4096 + o * 64 + dq * 16 + j] = acc[j];
}

// ---------------------------------------------------------------------------
// kE: out = M @ v, in-place over d_out (v packed hi<<16|lo). 1 px/thread.
// Grid: 1024 blocks x 256 thr.
// ---------------------------------------------------------------------------
__global__ __launch_bounds__(256)
void kE_out(const float* __restrict__ M, float* vout)
{
    __shared__ __attribute__((aligned(16))) float M_s[64][64];
    const int blk = blockIdx.x;
    const int b = blk >> 8, nb = blk & 255;
    const int tid = threadIdx.x;
    for (int i = tid; i < 4096; i += 256) M_s[i >> 6][i & 63] = M[b * 4096 + i];
    __syncthreads();

    const int n0 = nb * 256 + tid;
    float* vb = vout + ((size_t)b << 22);

    float vr[64];
    #pragma unroll
    for (int d = 0; d < 64; ++d) {
        const unsigned u = __float_as_uint(vb[((size_t)d << 16) + n0]);
        vr[d] = __uint_as_float(u & 0xFFFF0000u) + __uint_as_float(u << 16);
    }
    #pragma unroll 2
    for (int o = 0; o < 64; ++o) {
        float a0 = 0.f;
        #pragma unroll
        for (int dq = 0; dq < 16; ++dq) {
            const float4 m4 = *(const float4*)(&M_s[o][dq * 4]);
            a0 += m4.x * vr[dq*4+0];
            a0 += m4.y * vr[dq*4+1];
            a0 += m4.z * vr[dq*4+2];
            a0 += m4.w * vr[dq*4+3];
        }
        vb[((size_t)o << 16) + n0] = a0;
    }
}

// ===========================================================================
// FALLBACK PATH — round-1 kernels (used when ws_size is too small)
// ===========================================================================
__global__ __launch_bounds__(NT1)
void k1_fused(const float* __restrict__ x, const float* __restrict__ w_in,
              const float* __restrict__ w_dw, float* __restrict__ v_out,
              float* __restrict__ Gacc, float* __restrict__ sqq,
              float* __restrict__ sqv)
{
    __shared__ __attribute__((aligned(16))) float wT[64][256];
    __shared__ __attribute__((aligned(16))) float wdw_s[128][11];
    __shared__ __attribute__((aligned(16))) float xs[64][104];
    __shared__ __attribute__((aligned(16))) float t1s[64][105];
    __shared__ __attribute__((aligned(16))) float qvs[64][132];

    const int tid = threadIdx.x;
    const int blk = blockIdx.x;
    const int b = blk >> 6;
    const int bslot = blk & 63;

    for (int i = tid; i < 256 * 64; i += NT1) {
        int ch = i >> 6, c = i & 63;
        wT[c][ch] = w_in[i];
    }
    for (int i = tid; i < 128 * 9; i += NT1) {
        int ch = i / 9, k = i - ch * 9;
        wdw_s[ch][k] = w_dw[i];
    }

    const int gc0 = (tid >> 4) * 2;
    const int gd0 = (tid & 15) * 4;
    float g00 = 0, g01 = 0, g02 = 0, g03 = 0;
    float g10 = 0, g11 = 0, g12 = 0, g13 = 0;
    float sqreg = 0.f;

    const float* xb = x + ((size_t)b << 22);

    for (int tIdx = 0; tIdx < 16; ++tIdx) {
        const int tile = bslot + (tIdx << 6);
        const int ty0 = (tile >> 5) << 3;
        const int tx0 = (tile & 31) << 3;

        __syncthreads();

        for (int i = tid; i < 64 * 104; i += NT1) {
            int c = i / 104;
            int col = i - c * 104;
            float val = 0.f;
            if (col < 100) {
                int py = col / 10;
                int px = col - py * 10;
                int gy = ty0 - 1 + py;
                int gx = tx0 - 1 + px;
                if ((unsigned)gy < 256u && (unsigned)gx < 256u)
                    val = xb[((size_t)c << 16) + (gy << 8) + gx];
            }
            xs[c][col] = val;
        }
        __syncthreads();

        for (int h = 0; h < 2; ++h) {
            for (int it = tid; it < 672; it += NT1) {
                if (it < 416) {
                    const int chq = it / 26;
                    const int pq = it - chq * 26;
                    const int ch0 = (h << 6) + (chq << 2);
                    const int p0 = pq << 2;
                    float a00=0,a01=0,a02=0,a03=0, a10=0,a11=0,a12=0,a13=0;
                    float a20=0,a21=0,a22=0,a23=0, a30=0,a31=0,a32=0,a33=0;
                    #pragma unroll 4
                    for (int c = 0; c < 64; ++c) {
                        const float4 wv = *(const float4*)(&wT[c][ch0]);
                        const float4 xv = *(const float4*)(&xs[c][p0]);
                        a00 += wv.x*xv.x; a01 += wv.x*xv.y; a02 += wv.x*xv.z; a03 += wv.x*xv.w;
                        a10 += wv.y*xv.x; a11 += wv.y*xv.y; a12 += wv.y*xv.z; a13 += wv.y*xv.w;
                        a20 += wv.z*xv.x; a21 += wv.z*xv.y; a22 += wv.z*xv.z; a23 += wv.z*xv.w;
                        a30 += wv.w*xv.x; a31 += wv.w*xv.y; a32 += wv.w*xv.z; a33 += wv.w*xv.w;
                    }
                    const int lc = chq << 2;
                    t1s[lc+0][p0+0]=a00; t1s[lc+0][p0+1]=a01; t1s[lc+0][p0+2]=a02; t1s[lc+0][p0+3]=a03;
                    t1s[lc+1][p0+0]=a10; t1s[lc+1][p0+1]=a11; t1s[lc+1][p0+2]=a12; t1s[lc+1][p0+3]=a13;
                    t1s[lc+2][p0+0]=a20; t1s[lc+2][p0+1]=a21; t1s[lc+2][p0+2]=a22; t1s[lc+2][p0+3]=a23;
                    t1s[lc+3][p0+0]=a30; t1s[lc+3][p0+1]=a31; t1s[lc+3][p0+2]=a32; t1s[lc+3][p0+3]=a33;
                } else {
                    const int j = it - 416;
                    const int chq = j >> 4;
                    const int pq = j & 15;
                    const int ch0 = 128 + (h << 6) + (chq << 2);
                    const int p0 = pq << 2;
                    const int y = p0 >> 3, xc = p0 & 7;
                    const int hp0 = (y + 1) * 10 + xc + 1;
                    float a00=0,a01=0,a02=0,a03=0, a10=0,a11=0,a12=0,a13=0;
                    float a20=0,a21=0,a22=0,a23=0, a30=0,a31=0,a32=0,a33=0;
                    #pragma unroll 4
                    for (int c = 0; c < 64; ++c) {
                        const float4 wv = *(const float4*)(&wT[c][ch0]);
                        const float x0 = xs[c][hp0+0], x1 = xs[c][hp0+1];
                        const float x2 = xs[c][hp0+2], x3 = xs[c][hp0+3];
                        a00 += wv.x*x0; a01 += wv.x*x1; a02 += wv.x*x2; a03 += wv.x*x3;
                        a10 += wv.y*x0; a11 += wv.y*x1; a12 += wv.y*x2; a13 += wv.y*x3;
                        a20 += wv.z*x0; a21 += wv.z*x1; a22 += wv.z*x2; a23 += wv.z*x3;
                        a30 += wv.w*x0; a31 += wv.w*x1; a32 += wv.w*x2; a33 += wv.w*x3;
                    }
                    const int qc = (h << 6) + (chq << 2);
                    *(float4*)(&qvs[p0+0][qc]) = make_float4(a00, a10, a20, a30);
                    *(float4*)(&qvs[p0+1][qc]) = make_float4(a01, a11, a21, a31);
                    *(float4*)(&qvs[p0+2][qc]) = make_float4(a02, a12, a22, a32);
                    *(float4*)(&qvs[p0+3][qc]) = make_float4(a03, a13, a23, a33);
                }
            }
            __syncthreads();
            for (int it = tid; it < 4096; it += NT1) {
                const int ch = it & 63;
                const int p = it >> 6;
                const int y = p >> 3, xc = p & 7;
                const int base = y * 10 + xc;
                const float* wd = &wdw_s[(h << 6) + ch][0];
                float s = wd[0]*t1s[ch][base+ 0] + wd[1]*t1s[ch][base+ 1] + wd[2]*t1s[ch][base+ 2]
                        + wd[3]*t1s[ch][base+10] + wd[4]*t1s[ch][base+11] + wd[5]*t1s[ch][base+12]
                        + wd[6]*t1s[ch][base+20] + wd[7]*t1s[ch][base+21] + wd[8]*t1s[ch][base+22];
                const int qc = (h << 6) + ch;
                qvs[p][qc] = s * qvs[p][qc];
            }
            __syncthreads();
        }

        #pragma unroll 4
        for (int p = 0; p < 64; ++p) {
            const float2 q2 = *(const float2*)(&qvs[p][gc0]);
            const float4 v4 = *(const float4*)(&qvs[p][64 + gd0]);
            g00 += q2.x*v4.x; g01 += q2.x*v4.y; g02 += q2.x*v4.z; g03 += q2.x*v4.w;
            g10 += q2.y*v4.x; g11 += q2.y*v4.y; g12 += q2.y*v4.z; g13 += q2.y*v4.w;
        }
        if (tid < 128) {
            #pragma unroll 8
            for (int p = 0; p < 64; ++p) {
                const float val = qvs[p][tid];
                sqreg += val * val;
            }
        }
        for (int it = tid; it < 4096; it += NT1) {
            const int p = it & 63;
            const int d = it >> 6;
            const int gy = ty0 + (p >> 3), gx = tx0 + (p & 7);
            v_out[((size_t)(b * 64 + d) << 16) + (gy << 8) + gx] = qvs[p][64 + d];
        }
    }

    const int gb = b * 4096;
    atomicAdd(&Gacc[gb + (gc0 + 0) * 64 + gd0 + 0], g00);
    atomicAdd(&Gacc[gb + (gc0 + 0) * 64 + gd0 + 1], g01);
    atomicAdd(&Gacc[gb + (gc0 + 0) * 64 + gd0 + 2], g02);
    atomicAdd(&Gacc[gb + (gc0 + 0) * 64 + gd0 + 3], g03);
    atomicAdd(&Gacc[gb + (gc0 + 1) * 64 + gd0 + 0], g10);
    atomicAdd(&Gacc[gb + (gc0 + 1) * 64 + gd0 + 1], g11);
    atomicAdd(&Gacc[gb + (gc0 + 1) * 64 + gd0 + 2], g12);
    atomicAdd(&Gacc[gb + (gc0 + 1) * 64 + gd0 + 3], g13);
    if (tid < 64)       atomicAdd(&sqq[b * 64 + tid], sqreg);
    else if (tid < 128) atomicAdd(&sqv[b * 64 + tid - 64], sqreg);
}

__global__ __launch_bounds__(256)
void k3_out(const float* __restrict__ M, const float* v, float* out)
{
    __shared__ __attribute__((aligned(16))) float M_s[64][64];
    const int blk = blockIdx.x;
    const int b = blk >> 7;
    const int nb = blk & 127;
    const int tid = threadIdx.x;
    for (int i = tid; i < 4096; i += 256) M_s[i >> 6][i & 63] = M[b * 4096 + i];
    __syncthreads();

    const int n0 = nb * 512 + tid;
    const float* vb = v + ((size_t)b << 22);
    float* ob = out + ((size_t)b << 22);

    float vr0[64], vr1[64];
    #pragma unroll
    for (int d = 0; d < 64; ++d) {
        vr0[d] = vb[((size_t)d << 16) + n0];
        vr1[d] = vb[((size_t)d << 16) + n0 + 256];
    }
    for (int o = 0; o < 64; ++o) {
        float a0 = 0.f, a1 = 0.f;
        #pragma unroll
        for (int dq = 0; dq < 16; ++dq) {
            const float4 m4 = *(const float4*)(&M_s[o][dq * 4]);
            a0 += m4.x * vr0[dq*4+0]; a1 += m4.x * vr1[dq*4+0];
            a0 += m4.y * vr0[dq*4+1]; a1 += m4.y * vr1[dq*4+1];
            a0 += m4.z * vr0[dq*4+2]; a1 += m4.z * vr1[dq*4+2];
            a0 += m4.w * vr0[dq*4+3]; a1 += m4.w * vr1[dq*4+3];
        }
        ob[((size_t)o << 16) + n0] = a0;
        ob[((size_t)o << 16) + n0 + 256] = a1;
    }
}

// ===========================================================================
extern "C" void kernel_launch(void* const* d_in, const int* in_sizes, int n_in,
                              void* d_out, int out_size, void* d_ws, size_t ws_size,
                              hipStream_t stream)
{
    (void)in_sizes; (void)n_in; (void)out_size;
    const float* x     = (const float*)d_in[0];
    const float* w_in  = (const float*)d_in[1];
    const float* w_dw  = (const float*)d_in[2];
    const float* w_out = (const float*)d_in[3];
    const float* temp  = (const float*)d_in[4];
    float* out = (float*)d_out;

    // fast-path workspace layout (bytes)
    const size_t OFF_QH    = 0;                   // 33554432 (q bf16 planes)
    const size_t OFF_GPART = 33554432;            // 33554432 (2048 x 16KB)
    const size_t OFF_GRED  = 67108864;            // 65536
    const size_t OFF_SQQ   = 67174400;            // 1024
    const size_t OFF_SQV   = 67175424;            // 1024
    const size_t OFF_M     = 67176448;            // 65536
    const size_t NEED      = 67241984;            // ~64.1 MiB

    if (ws_size >= NEED) {
        char* ws = (char*)d_ws;
        unsigned short* qh = (unsigned short*)(ws + OFF_QH);
        float* Gpart = (float*)(ws + OFF_GPART);
        float* Gred  = (float*)(ws + OFF_GRED);
        float* sqq   = (float*)(ws + OFF_SQQ);
        float* sqv   = (float*)(ws + OFF_SQV);
        float* Mws   = (float*)(ws + OFF_M);

        hipMemsetAsync((void*)sqq, 0, 2048, stream);
        hipLaunchKernelGGL(kQ_half, dim3(2048), dim3(256), 0, stream,
                           x, w_in, w_dw, qh, (unsigned*)d_out, sqq, sqv);
        hipLaunchKernelGGL(kG_gemm, dim3(512), dim3(256), 0, stream,
                           qh, (const unsigned*)d_out, Gpart);
        hipLaunchKernelGGL(kR_red, dim3(64), dim3(256), 0, stream, Gpart, Gred);
        hipLaunchKernelGGL(kD_softmax, dim3(4), dim3(256), 0, stream,
                           Gred, sqq, sqv, temp, w_out, Mws);
        hipLaunchKernelGGL(kE_out, dim3(1024), dim3(256), 0, stream, Mws, out);
    } else {
        // fallback: round-1 path (~133 KiB ws)
        float* Gacc = (float*)d_ws;
        float* sqq  = Gacc + 16384;
        float* sqv  = sqq + 256;
        float* Mws  = sqv + 256;
        hipMemsetAsync((void*)Gacc, 0, (16384 + 512) * sizeof(float), stream);
        hipLaunchKernelGGL(k1_fused, dim3(256), dim3(NT1), 0, stream,
                           x, w_in, w_dw, out, Gacc, sqq, sqv);
        hipLaunchKernelGGL(kD_softmax, dim3(4), dim3(256), 0, stream,
                           Gacc, sqq, sqv, temp, w_out, Mws);
        hipLaunchKernelGGL(k3_out, dim3(512), dim3(256), 0, stream,
                           Mws, out, out);
    }
}